// Round 1
// baseline (498.223 us; speedup 1.0000x reference)
//
#include <hip/hip_runtime.h>
#include <math.h>

// ---------------------------------------------------------------------------
// GAT node classifier: 2x GATConv(H=2, concat=False/head-mean) + Linear.
// Pipeline per launch:
//   1. build CSR over dst (degree atomics -> 1-block scan -> atomic scatter)
//   2. h1 = x @ W1           (fp32 GEMM, N x 128 x 128)
//   3. al_s/al_d from h1
//   4. agg1: segment softmax over incoming edges + weighted sum, head-mean,
//            +b1, ReLU  -> B [N,64]
//   5. h2 = B @ W2, al, agg2 (+b2, no relu) -> B [N,64]
//   6. preds = B @ Wc + bc -> d_out[0 .. N*10)
//   7. y copied (as float) to d_out[N*10 ..)
// ---------------------------------------------------------------------------

__device__ __forceinline__ float lrelu(float x) { return x > 0.f ? x : 0.2f * x; }

__global__ void deg_kernel(const int* __restrict__ dst, int* cnt, int e) {
    int i = blockIdx.x * 256 + threadIdx.x;
    if (i < e) atomicAdd(&cnt[dst[i]], 1);
}

// single-block exclusive scan of cnt[0..n) -> rowptr[0..n], cursor=rowptr copy.
// In-place safe: cnt IS cursor.
__global__ __launch_bounds__(256) void scan_kernel(int* cursor, int* rowptr, int n) {
    __shared__ int sums[256];
    int tid = threadIdx.x;
    int chunk = (n + 255) / 256;
    int start = tid * chunk;
    int end = min(start + chunk, n);
    int s = 0;
    for (int i = start; i < end; ++i) s += cursor[i];
    sums[tid] = s;
    __syncthreads();
    if (tid == 0) {
        int acc = 0;
        for (int j = 0; j < 256; ++j) { int t = sums[j]; sums[j] = acc; acc += t; }
        rowptr[n] = acc;
    }
    __syncthreads();
    int run = sums[tid];
    for (int i = start; i < end; ++i) {
        int v = cursor[i];
        rowptr[i] = run;
        cursor[i] = run;
        run += v;
    }
}

__global__ void scatter_kernel(const int* __restrict__ src, const int* __restrict__ dst,
                               int* cursor, int* __restrict__ csr_src, int e) {
    int i = blockIdx.x * 256 + threadIdx.x;
    if (i < e) {
        int d = dst[i];
        int pos = atomicAdd(&cursor[d], 1);
        csr_src[pos] = src[i];
    }
}

// X [n,K] @ W [K,128] -> H [n,128].  16 rows/block, 256 threads,
// each thread computes 1 row x 8 cols.
template <int K>
__global__ __launch_bounds__(256) void gemm_nodes(const float* __restrict__ X,
                                                  const float* __restrict__ W,
                                                  float* __restrict__ H, int n) {
    __shared__ float sW[K][128];
    __shared__ float sX[16][K];
    int tid = threadIdx.x;
    for (int i = tid; i < K * 128; i += 256) sW[i >> 7][i & 127] = W[i];
    int row0 = blockIdx.x * 16;
    for (int i = tid; i < 16 * K; i += 256) {
        int r = i / K, k = i % K;
        int gr = row0 + r;
        sX[r][k] = (gr < n) ? X[(size_t)gr * K + k] : 0.f;
    }
    __syncthreads();
    int r = tid >> 4;
    int c0 = (tid & 15) * 8;
    float acc[8] = {0.f, 0.f, 0.f, 0.f, 0.f, 0.f, 0.f, 0.f};
    for (int k = 0; k < K; ++k) {
        float xv = sX[r][k];
        const float4* wrow = reinterpret_cast<const float4*>(&sW[k][c0]);
        float4 w0 = wrow[0], w1 = wrow[1];
        acc[0] += xv * w0.x; acc[1] += xv * w0.y;
        acc[2] += xv * w0.z; acc[3] += xv * w0.w;
        acc[4] += xv * w1.x; acc[5] += xv * w1.y;
        acc[6] += xv * w1.z; acc[7] += xv * w1.w;
    }
    int gr = row0 + r;
    if (gr < n) {
        float4* o = reinterpret_cast<float4*>(&H[(size_t)gr * 128 + c0]);
        o[0] = make_float4(acc[0], acc[1], acc[2], acc[3]);
        o[1] = make_float4(acc[4], acc[5], acc[6], acc[7]);
    }
}

// al_s[n][h] = sum_c h[n,h,c]*a_src[h,c]; one wave per node.
__global__ __launch_bounds__(256) void al_kernel(const float* __restrict__ Hf,
                                                 const float* __restrict__ a_src,
                                                 const float* __restrict__ a_dst,
                                                 float* __restrict__ als,
                                                 float* __restrict__ ald, int n) {
    int wave = threadIdx.x >> 6, lane = threadIdx.x & 63;
    int node = blockIdx.x * 4 + wave;
    if (node >= n) return;
    float v0 = Hf[(size_t)node * 128 + lane];
    float v1 = Hf[(size_t)node * 128 + 64 + lane];
    float s0 = v0 * a_src[lane], s1 = v1 * a_src[64 + lane];
    float d0 = v0 * a_dst[lane], d1 = v1 * a_dst[64 + lane];
    for (int off = 32; off; off >>= 1) {
        s0 += __shfl_xor(s0, off);
        s1 += __shfl_xor(s1, off);
        d0 += __shfl_xor(d0, off);
        d1 += __shfl_xor(d1, off);
    }
    if (lane == 0) {
        als[node * 2] = s0; als[node * 2 + 1] = s1;
        ald[node * 2] = d0; ald[node * 2 + 1] = d1;
    }
}

// One wave per dst node. Lanes own edges for (e,max,p), then own channel
// pairs for the weighted feature gather; shfl broadcasts (src,p) per edge.
template <bool RELU>
__global__ __launch_bounds__(256) void agg_kernel(const float* __restrict__ Hf,
                                                  const float* __restrict__ als,
                                                  const float* __restrict__ ald,
                                                  const int* __restrict__ rowptr,
                                                  const int* __restrict__ csr_src,
                                                  const float* __restrict__ bias,
                                                  float* __restrict__ out, int n) {
    int wave = threadIdx.x >> 6, lane = threadIdx.x & 63;
    int node = blockIdx.x * 4 + wave;
    if (node >= n) return;
    int beg = rowptr[node], end = rowptr[node + 1];
    float ad0 = ald[node * 2], ad1 = ald[node * 2 + 1];

    // pass A: segment max (lanes own edges)
    float m0 = -INFINITY, m1 = -INFINITY;
    for (int c = beg; c < end; c += 64) {
        int j = c + lane;
        if (j < end) {
            int s = csr_src[j];
            float e0 = lrelu(als[s * 2] + ad0);
            float e1 = lrelu(als[s * 2 + 1] + ad1);
            m0 = fmaxf(m0, e0);
            m1 = fmaxf(m1, e1);
        }
    }
    for (int off = 32; off; off >>= 1) {
        m0 = fmaxf(m0, __shfl_xor(m0, off));
        m1 = fmaxf(m1, __shfl_xor(m1, off));
    }

    // pass B: p = exp(e-m), z = sum p, acc = sum p * h[src]
    float z0 = 0.f, z1 = 0.f;
    float accx = 0.f, accy = 0.f;  // lane owns channels (2*lane, 2*lane+1) of [H*64]
    for (int c = beg; c < end; c += 64) {
        int j = c + lane;
        int s = 0;
        float p0 = 0.f, p1 = 0.f;
        if (j < end) {
            s = csr_src[j];
            float e0 = lrelu(als[s * 2] + ad0);
            float e1 = lrelu(als[s * 2 + 1] + ad1);
            p0 = __expf(e0 - m0);
            p1 = __expf(e1 - m1);
        }
        z0 += p0;
        z1 += p1;
        int cnt = min(64, end - c);
        for (int t = 0; t < cnt; ++t) {
            int sj = __shfl(s, t);
            float pj0 = __shfl(p0, t);
            float pj1 = __shfl(p1, t);
            float psel = (lane < 32) ? pj0 : pj1;
            const float2 hv = *reinterpret_cast<const float2*>(&Hf[(size_t)sj * 128 + lane * 2]);
            accx += psel * hv.x;
            accy += psel * hv.y;
        }
    }
    for (int off = 32; off; off >>= 1) {
        z0 += __shfl_xor(z0, off);
        z1 += __shfl_xor(z1, off);
    }
    float zsel = (lane < 32) ? z0 : z1;
    float vx = accx / zsel, vy = accy / zsel;
    float ox = vx + __shfl_xor(vx, 32);  // head0 + head1 for channel 2*(lane&31)
    float oy = vy + __shfl_xor(vy, 32);
    if (lane < 32) {
        int ch = lane * 2;
        float r0 = 0.5f * ox + bias[ch];
        float r1 = 0.5f * oy + bias[ch + 1];
        if (RELU) {
            r0 = fmaxf(r0, 0.f);
            r1 = fmaxf(r1, 0.f);
        }
        *reinterpret_cast<float2*>(&out[(size_t)node * 64 + ch]) = make_float2(r0, r1);
    }
}

// preds = Hf [n,64] @ Wc [64,10] + bc; one thread per node.
__global__ __launch_bounds__(256) void cls_kernel(const float* __restrict__ Hf,
                                                  const float* __restrict__ Wc,
                                                  const float* __restrict__ bc,
                                                  float* __restrict__ out, int n) {
    __shared__ float sW[640];
    __shared__ float sb[10];
    int tid = threadIdx.x;
    for (int i = tid; i < 640; i += 256) sW[i] = Wc[i];
    if (tid < 10) sb[tid] = bc[tid];
    __syncthreads();
    int node = blockIdx.x * 256 + tid;
    if (node >= n) return;
    float acc[10];
#pragma unroll
    for (int j = 0; j < 10; ++j) acc[j] = sb[j];
    for (int k = 0; k < 64; k += 4) {
        float4 h4 = *reinterpret_cast<const float4*>(&Hf[(size_t)node * 64 + k]);
#pragma unroll
        for (int j = 0; j < 10; ++j) {
            acc[j] += h4.x * sW[(k + 0) * 10 + j];
            acc[j] += h4.y * sW[(k + 1) * 10 + j];
            acc[j] += h4.z * sW[(k + 2) * 10 + j];
            acc[j] += h4.w * sW[(k + 3) * 10 + j];
        }
    }
#pragma unroll
    for (int j = 0; j < 10; ++j) out[(size_t)node * 10 + j] = acc[j];
}

__global__ void ycopy_kernel(const int* __restrict__ y, float* __restrict__ out, int n) {
    int i = blockIdx.x * 256 + threadIdx.x;
    if (i < n) out[i] = (float)y[i];
}

extern "C" void kernel_launch(void* const* d_in, const int* in_sizes, int n_in,
                              void* d_out, int out_size, void* d_ws, size_t ws_size,
                              hipStream_t stream) {
    const float* x   = (const float*)d_in[0];
    const int*   ei  = (const int*)d_in[1];
    const int*   y   = (const int*)d_in[3];
    const float* W1  = (const float*)d_in[4];
    const float* as1 = (const float*)d_in[5];
    const float* ad1 = (const float*)d_in[6];
    const float* b1  = (const float*)d_in[7];
    const float* W2  = (const float*)d_in[8];
    const float* as2 = (const float*)d_in[9];
    const float* ad2 = (const float*)d_in[10];
    const float* b2  = (const float*)d_in[11];
    const float* Wc  = (const float*)d_in[12];
    const float* bc  = (const float*)d_in[13];

    int n = in_sizes[0] / 128;   // 50000
    int e = in_sizes[1] / 2;     // 850000
    const int* src = ei;
    const int* dst = ei + e;

    char* ws = (char*)d_ws;
    size_t off = 0;
    auto alloc = [&](size_t bytes) -> void* {
        void* p = ws + off;
        off = (off + bytes + 255) & ~size_t(255);
        return p;
    };
    float* A       = (float*)alloc((size_t)n * 128 * 4);  // h (pre-agg) both layers
    float* B       = (float*)alloc((size_t)n * 64 * 4);   // layer outputs
    float* als     = (float*)alloc((size_t)n * 2 * 4);
    float* ald     = (float*)alloc((size_t)n * 2 * 4);
    int*   rowptr  = (int*)alloc((size_t)(n + 1) * 4);
    int*   cursor  = (int*)alloc((size_t)n * 4);
    int*   csr_src = (int*)alloc((size_t)e * 4);

    float* preds = (float*)d_out;
    float* yout  = preds + (size_t)n * 10;

    int eb = (e + 255) / 256;
    int nb4 = (n + 3) / 4;
    int nb16 = (n + 15) / 16;
    int nb256 = (n + 255) / 256;

    // CSR by dst (rebuilt every call: no cross-call state allowed)
    hipMemsetAsync(cursor, 0, (size_t)n * 4, stream);
    deg_kernel<<<eb, 256, 0, stream>>>(dst, cursor, e);
    scan_kernel<<<1, 256, 0, stream>>>(cursor, rowptr, n);
    scatter_kernel<<<eb, 256, 0, stream>>>(src, dst, cursor, csr_src, e);

    // layer 1
    gemm_nodes<128><<<nb16, 256, 0, stream>>>(x, W1, A, n);
    al_kernel<<<nb4, 256, 0, stream>>>(A, as1, ad1, als, ald, n);
    agg_kernel<true><<<nb4, 256, 0, stream>>>(A, als, ald, rowptr, csr_src, b1, B, n);

    // layer 2
    gemm_nodes<64><<<nb16, 256, 0, stream>>>(B, W2, A, n);
    al_kernel<<<nb4, 256, 0, stream>>>(A, as2, ad2, als, ald, n);
    agg_kernel<false><<<nb4, 256, 0, stream>>>(A, als, ald, rowptr, csr_src, b2, B, n);

    // classifier + y passthrough
    cls_kernel<<<nb256, 256, 0, stream>>>(B, Wc, bc, preds, n);
    ycopy_kernel<<<nb256, 256, 0, stream>>>(y, yout, n);
}

// Round 2
// 351.545 us; speedup vs baseline: 1.4172x; 1.4172x over previous
//
#include <hip/hip_runtime.h>
#include <math.h>

// ---------------------------------------------------------------------------
// GAT node classifier: 2x GATConv(H=2, concat=False/head-mean) + Linear.
//   1. CSR by dst: degree atomics -> hierarchical parallel scan -> scatter
//   2. h = X @ W (fp32) with fused attention-logit epilogue (als/ald)
//   3. agg: segment softmax over incoming edges + weighted sum, head-mean,
//      +bias, optional ReLU
//   4. preds = B @ Wc + bc ; y passthrough
// ---------------------------------------------------------------------------

__device__ __forceinline__ float lrelu(float x) { return x > 0.f ? x : 0.2f * x; }

__global__ void deg_kernel(const int* __restrict__ dst, int* cnt, int e) {
    int i = blockIdx.x * 256 + threadIdx.x;
    if (i < e) atomicAdd(&cnt[dst[i]], 1);
}

// ---- hierarchical scan: deg[0..n) -> rowptr[0..n], cursor copy ----
__global__ __launch_bounds__(256) void block_sums(const int* __restrict__ deg,
                                                  int* __restrict__ bsum, int n) {
    int i = blockIdx.x * 256 + threadIdx.x;
    int v = (i < n) ? deg[i] : 0;
    for (int off = 32; off; off >>= 1) v += __shfl_xor(v, off);
    __shared__ int ws[4];
    if ((threadIdx.x & 63) == 0) ws[threadIdx.x >> 6] = v;
    __syncthreads();
    if (threadIdx.x == 0) bsum[blockIdx.x] = ws[0] + ws[1] + ws[2] + ws[3];
}

// single block: exclusive scan of bsum[0..nb), nb<=256; writes rowptr[n]=total
__global__ __launch_bounds__(256) void scan_partials(int* bsum, int* rowptr, int nb, int n) {
    __shared__ int s[256];
    int tid = threadIdx.x;
    s[tid] = (tid < nb) ? bsum[tid] : 0;
    __syncthreads();
    if (tid == 0) {
        int acc = 0;
        for (int j = 0; j < nb; ++j) { int t = s[j]; s[j] = acc; acc += t; }
        rowptr[n] = acc;
    }
    __syncthreads();
    if (tid < nb) bsum[tid] = s[tid];
}

// per-block intra-scan + block offset -> rowptr, cursor
__global__ __launch_bounds__(256) void scan_blocks(const int* __restrict__ deg,
                                                   const int* __restrict__ bsum,
                                                   int* __restrict__ rowptr,
                                                   int* __restrict__ cursor, int n) {
    int tid = threadIdx.x;
    int i = blockIdx.x * 256 + tid;
    int v = (i < n) ? deg[i] : 0;
    int lane = tid & 63, w = tid >> 6;
    int x = v;
    for (int off = 1; off < 64; off <<= 1) {
        int t = __shfl_up(x, off);
        if (lane >= off) x += t;
    }
    __shared__ int wsum[4];
    if (lane == 63) wsum[w] = x;
    __syncthreads();
    int wo = 0;
    for (int j = 0; j < w; ++j) wo += wsum[j];
    int excl = bsum[blockIdx.x] + wo + x - v;
    if (i < n) { rowptr[i] = excl; cursor[i] = excl; }
}

__global__ void scatter_kernel(const int* __restrict__ src, const int* __restrict__ dst,
                               int* cursor, int* __restrict__ csr_src, int e) {
    int i = blockIdx.x * 256 + threadIdx.x;
    if (i < e) {
        int d = dst[i];
        int pos = atomicAdd(&cursor[d], 1);
        csr_src[pos] = src[i];
    }
}

// X [n,K] @ W [K,128] -> H [n,128], with fused attention logits:
// als[g,h] = sum_c H[g, h*64+c] * a_src[h*64+c]  (same for ald / a_dst).
// 16 rows/block, 256 threads, each thread 1 row x 8 cols.
template <int K>
__global__ __launch_bounds__(256) void gemm_nodes(const float* __restrict__ X,
                                                  const float* __restrict__ W,
                                                  const float* __restrict__ a_src,
                                                  const float* __restrict__ a_dst,
                                                  float* __restrict__ H,
                                                  float* __restrict__ als,
                                                  float* __restrict__ ald, int n) {
    __shared__ float sW[K][128];
    __shared__ float sX[16][K];
    int tid = threadIdx.x;
    for (int i = tid; i < K * 128; i += 256) sW[i >> 7][i & 127] = W[i];
    int row0 = blockIdx.x * 16;
    for (int i = tid; i < 16 * K; i += 256) {
        int r = i / K, k = i % K;
        int gr = row0 + r;
        sX[r][k] = (gr < n) ? X[(size_t)gr * K + k] : 0.f;
    }
    __syncthreads();
    int r = tid >> 4;
    int c0 = (tid & 15) * 8;
    float acc[8] = {0.f, 0.f, 0.f, 0.f, 0.f, 0.f, 0.f, 0.f};
    for (int k = 0; k < K; ++k) {
        float xv = sX[r][k];
        const float4* wrow = reinterpret_cast<const float4*>(&sW[k][c0]);
        float4 w0 = wrow[0], w1 = wrow[1];
        acc[0] += xv * w0.x; acc[1] += xv * w0.y;
        acc[2] += xv * w0.z; acc[3] += xv * w0.w;
        acc[4] += xv * w1.x; acc[5] += xv * w1.y;
        acc[6] += xv * w1.z; acc[7] += xv * w1.w;
    }
    int gr = row0 + r;
    if (gr < n) {
        float4* o = reinterpret_cast<float4*>(&H[(size_t)gr * 128 + c0]);
        o[0] = make_float4(acc[0], acc[1], acc[2], acc[3]);
        o[1] = make_float4(acc[4], acc[5], acc[6], acc[7]);
    }
    // fused attention-logit epilogue
    __shared__ float rs[16][17];
    __shared__ float rd[16][17];
    float ps = 0.f, pd = 0.f;
#pragma unroll
    for (int j = 0; j < 8; ++j) {
        ps += acc[j] * a_src[c0 + j];
        pd += acc[j] * a_dst[c0 + j];
    }
    rs[r][tid & 15] = ps;
    rd[r][tid & 15] = pd;
    __syncthreads();
    if (tid < 64) {
        int ri = tid >> 2, rem = tid & 3, h = rem >> 1, sd = rem & 1;
        int gr2 = row0 + ri;
        if (gr2 < n) {
            float sum = 0.f;
            if (sd == 0) {
#pragma unroll
                for (int j = 0; j < 8; ++j) sum += rs[ri][h * 8 + j];
                als[gr2 * 2 + h] = sum;
            } else {
#pragma unroll
                for (int j = 0; j < 8; ++j) sum += rd[ri][h * 8 + j];
                ald[gr2 * 2 + h] = sum;
            }
        }
    }
}

// One wave per dst node. Lanes own edges for (e,max,p), then own channel
// pairs for the weighted feature gather; shfl broadcasts (src,p) per edge.
template <bool RELU>
__global__ __launch_bounds__(256) void agg_kernel(const float* __restrict__ Hf,
                                                  const float* __restrict__ als,
                                                  const float* __restrict__ ald,
                                                  const int* __restrict__ rowptr,
                                                  const int* __restrict__ csr_src,
                                                  const float* __restrict__ bias,
                                                  float* __restrict__ out, int n) {
    int wave = threadIdx.x >> 6, lane = threadIdx.x & 63;
    int node = blockIdx.x * 4 + wave;
    if (node >= n) return;
    int beg = rowptr[node], end = rowptr[node + 1];
    float ad0 = ald[node * 2], ad1 = ald[node * 2 + 1];

    // pass A: segment max (lanes own edges)
    float m0 = -INFINITY, m1 = -INFINITY;
    for (int c = beg; c < end; c += 64) {
        int j = c + lane;
        if (j < end) {
            int s = csr_src[j];
            float e0 = lrelu(als[s * 2] + ad0);
            float e1 = lrelu(als[s * 2 + 1] + ad1);
            m0 = fmaxf(m0, e0);
            m1 = fmaxf(m1, e1);
        }
    }
    for (int off = 32; off; off >>= 1) {
        m0 = fmaxf(m0, __shfl_xor(m0, off));
        m1 = fmaxf(m1, __shfl_xor(m1, off));
    }

    // pass B: p = exp(e-m), z = sum p, acc = sum p * h[src]
    float z0 = 0.f, z1 = 0.f;
    float accx = 0.f, accy = 0.f;  // lane owns channels (2*lane, 2*lane+1) of [H*64]
    for (int c = beg; c < end; c += 64) {
        int j = c + lane;
        int s = 0;
        float p0 = 0.f, p1 = 0.f;
        if (j < end) {
            s = csr_src[j];
            float e0 = lrelu(als[s * 2] + ad0);
            float e1 = lrelu(als[s * 2 + 1] + ad1);
            p0 = __expf(e0 - m0);
            p1 = __expf(e1 - m1);
        }
        z0 += p0;
        z1 += p1;
        int cnt = min(64, end - c);
        for (int t = 0; t < cnt; ++t) {
            int sj = __shfl(s, t);
            float pj0 = __shfl(p0, t);
            float pj1 = __shfl(p1, t);
            float psel = (lane < 32) ? pj0 : pj1;
            const float2 hv = *reinterpret_cast<const float2*>(&Hf[(size_t)sj * 128 + lane * 2]);
            accx += psel * hv.x;
            accy += psel * hv.y;
        }
    }
    for (int off = 32; off; off >>= 1) {
        z0 += __shfl_xor(z0, off);
        z1 += __shfl_xor(z1, off);
    }
    float zsel = (lane < 32) ? z0 : z1;
    float vx = accx / zsel, vy = accy / zsel;
    float ox = vx + __shfl_xor(vx, 32);  // head0 + head1 for channel 2*(lane&31)
    float oy = vy + __shfl_xor(vy, 32);
    if (lane < 32) {
        int ch = lane * 2;
        float r0 = 0.5f * ox + bias[ch];
        float r1 = 0.5f * oy + bias[ch + 1];
        if (RELU) {
            r0 = fmaxf(r0, 0.f);
            r1 = fmaxf(r1, 0.f);
        }
        *reinterpret_cast<float2*>(&out[(size_t)node * 64 + ch]) = make_float2(r0, r1);
    }
}

// preds = Hf [n,64] @ Wc [64,10] + bc; one thread per node.
__global__ __launch_bounds__(256) void cls_kernel(const float* __restrict__ Hf,
                                                  const float* __restrict__ Wc,
                                                  const float* __restrict__ bc,
                                                  float* __restrict__ out, int n) {
    __shared__ float sW[640];
    __shared__ float sb[10];
    int tid = threadIdx.x;
    for (int i = tid; i < 640; i += 256) sW[i] = Wc[i];
    if (tid < 10) sb[tid] = bc[tid];
    __syncthreads();
    int node = blockIdx.x * 256 + tid;
    if (node >= n) return;
    float acc[10];
#pragma unroll
    for (int j = 0; j < 10; ++j) acc[j] = sb[j];
    for (int k = 0; k < 64; k += 4) {
        float4 h4 = *reinterpret_cast<const float4*>(&Hf[(size_t)node * 64 + k]);
#pragma unroll
        for (int j = 0; j < 10; ++j) {
            acc[j] += h4.x * sW[(k + 0) * 10 + j];
            acc[j] += h4.y * sW[(k + 1) * 10 + j];
            acc[j] += h4.z * sW[(k + 2) * 10 + j];
            acc[j] += h4.w * sW[(k + 3) * 10 + j];
        }
    }
#pragma unroll
    for (int j = 0; j < 10; ++j) out[(size_t)node * 10 + j] = acc[j];
}

__global__ void ycopy_kernel(const int* __restrict__ y, float* __restrict__ out, int n) {
    int i = blockIdx.x * 256 + threadIdx.x;
    if (i < n) out[i] = (float)y[i];
}

extern "C" void kernel_launch(void* const* d_in, const int* in_sizes, int n_in,
                              void* d_out, int out_size, void* d_ws, size_t ws_size,
                              hipStream_t stream) {
    const float* x   = (const float*)d_in[0];
    const int*   ei  = (const int*)d_in[1];
    const int*   y   = (const int*)d_in[3];
    const float* W1  = (const float*)d_in[4];
    const float* as1 = (const float*)d_in[5];
    const float* ad1 = (const float*)d_in[6];
    const float* b1  = (const float*)d_in[7];
    const float* W2  = (const float*)d_in[8];
    const float* as2 = (const float*)d_in[9];
    const float* ad2 = (const float*)d_in[10];
    const float* b2  = (const float*)d_in[11];
    const float* Wc  = (const float*)d_in[12];
    const float* bc  = (const float*)d_in[13];

    int n = in_sizes[0] / 128;   // 50000
    int e = in_sizes[1] / 2;     // 850000
    const int* src = ei;
    const int* dst = ei + e;

    char* ws = (char*)d_ws;
    size_t off = 0;
    auto alloc = [&](size_t bytes) -> void* {
        void* p = ws + off;
        off = (off + bytes + 255) & ~size_t(255);
        return p;
    };
    float* A       = (float*)alloc((size_t)n * 128 * 4);  // h (pre-agg) both layers
    float* B       = (float*)alloc((size_t)n * 64 * 4);   // layer outputs
    float* als     = (float*)alloc((size_t)n * 2 * 4);
    float* ald     = (float*)alloc((size_t)n * 2 * 4);
    int*   rowptr  = (int*)alloc((size_t)(n + 1) * 4);
    int*   cursor  = (int*)alloc((size_t)n * 4);
    int*   deg     = (int*)alloc((size_t)n * 4);
    int*   bsum    = (int*)alloc((size_t)256 * 4);
    int*   csr_src = (int*)alloc((size_t)e * 4);

    float* preds = (float*)d_out;
    float* yout  = preds + (size_t)n * 10;

    int eb = (e + 255) / 256;
    int nb4 = (n + 3) / 4;
    int nb16 = (n + 15) / 16;
    int nb256 = (n + 255) / 256;  // also the scan block count (n/256)

    // CSR by dst (rebuilt every call: no cross-call state allowed)
    hipMemsetAsync(deg, 0, (size_t)n * 4, stream);
    deg_kernel<<<eb, 256, 0, stream>>>(dst, deg, e);
    block_sums<<<nb256, 256, 0, stream>>>(deg, bsum, n);
    scan_partials<<<1, 256, 0, stream>>>(bsum, rowptr, nb256, n);
    scan_blocks<<<nb256, 256, 0, stream>>>(deg, bsum, rowptr, cursor, n);
    scatter_kernel<<<eb, 256, 0, stream>>>(src, dst, cursor, csr_src, e);

    // layer 1
    gemm_nodes<128><<<nb16, 256, 0, stream>>>(x, W1, as1, ad1, A, als, ald, n);
    agg_kernel<true><<<nb4, 256, 0, stream>>>(A, als, ald, rowptr, csr_src, b1, B, n);

    // layer 2
    gemm_nodes<64><<<nb16, 256, 0, stream>>>(B, W2, as2, ad2, A, als, ald, n);
    agg_kernel<false><<<nb4, 256, 0, stream>>>(A, als, ald, rowptr, csr_src, b2, B, n);

    // classifier + y passthrough
    cls_kernel<<<nb256, 256, 0, stream>>>(B, Wc, bc, preds, n);
    ycopy_kernel<<<nb256, 256, 0, stream>>>(y, yout, n);
}

// Round 3
// 300.697 us; speedup vs baseline: 1.6569x; 1.1691x over previous
//
#include <hip/hip_runtime.h>
#include <math.h>

// ---------------------------------------------------------------------------
// GAT node classifier: 2x GATConv(H=2, concat=False/head-mean) + Linear.
//   1. CSR by dst: degree atomics -> hierarchical parallel scan -> scatter
//   2. h = X @ W (fp32, 64 rows/block, 4x8 reg tile, K-chunked LDS) with
//      fused attention-logit epilogue (als/ald) via in-wave shfl reduce
//   3. agg: segment softmax over incoming edges + weighted sum, head-mean
//   4. preds = B @ Wc + bc ; y passthrough
// ---------------------------------------------------------------------------

__device__ __forceinline__ float lrelu(float x) { return x > 0.f ? x : 0.2f * x; }

__global__ void deg_kernel(const int* __restrict__ dst, int* cnt, int e) {
    int i = blockIdx.x * 256 + threadIdx.x;
    if (i < e) atomicAdd(&cnt[dst[i]], 1);
}

// ---- hierarchical scan: deg[0..n) -> rowptr[0..n], cursor copy ----
__global__ __launch_bounds__(256) void block_sums(const int* __restrict__ deg,
                                                  int* __restrict__ bsum, int n) {
    int i = blockIdx.x * 256 + threadIdx.x;
    int v = (i < n) ? deg[i] : 0;
    for (int off = 32; off; off >>= 1) v += __shfl_xor(v, off);
    __shared__ int ws[4];
    if ((threadIdx.x & 63) == 0) ws[threadIdx.x >> 6] = v;
    __syncthreads();
    if (threadIdx.x == 0) bsum[blockIdx.x] = ws[0] + ws[1] + ws[2] + ws[3];
}

// single block: exclusive scan of bsum[0..nb), nb<=256; writes rowptr[n]=total
__global__ __launch_bounds__(256) void scan_partials(int* bsum, int* rowptr, int nb, int n) {
    __shared__ int s[256];
    int tid = threadIdx.x;
    s[tid] = (tid < nb) ? bsum[tid] : 0;
    __syncthreads();
    if (tid == 0) {
        int acc = 0;
        for (int j = 0; j < nb; ++j) { int t = s[j]; s[j] = acc; acc += t; }
        rowptr[n] = acc;
    }
    __syncthreads();
    if (tid < nb) bsum[tid] = s[tid];
}

// per-block intra-scan + block offset -> rowptr, cursor
__global__ __launch_bounds__(256) void scan_blocks(const int* __restrict__ deg,
                                                   const int* __restrict__ bsum,
                                                   int* __restrict__ rowptr,
                                                   int* __restrict__ cursor, int n) {
    int tid = threadIdx.x;
    int i = blockIdx.x * 256 + tid;
    int v = (i < n) ? deg[i] : 0;
    int lane = tid & 63, w = tid >> 6;
    int x = v;
    for (int off = 1; off < 64; off <<= 1) {
        int t = __shfl_up(x, off);
        if (lane >= off) x += t;
    }
    __shared__ int wsum[4];
    if (lane == 63) wsum[w] = x;
    __syncthreads();
    int wo = 0;
    for (int j = 0; j < w; ++j) wo += wsum[j];
    int excl = bsum[blockIdx.x] + wo + x - v;
    if (i < n) { rowptr[i] = excl; cursor[i] = excl; }
}

__global__ void scatter_kernel(const int* __restrict__ src, const int* __restrict__ dst,
                               int* cursor, int* __restrict__ csr_src, int e) {
    int i = blockIdx.x * 256 + threadIdx.x;
    if (i < e) {
        int d = dst[i];
        int pos = atomicAdd(&cursor[d], 1);
        csr_src[pos] = src[i];
    }
}

// X [n,K] @ W [K,128] -> H [n,128], fused attention logits.
// 64 rows/block, 256 threads (16 row-groups x 16 col-groups), 4x8 reg tile,
// K staged in chunks of 32. sX padded to 33 (conflict-free column reads).
template <int K>
__global__ __launch_bounds__(256) void gemm_nodes(const float* __restrict__ X,
                                                  const float* __restrict__ W,
                                                  const float* __restrict__ a_src,
                                                  const float* __restrict__ a_dst,
                                                  float* __restrict__ H,
                                                  float* __restrict__ als,
                                                  float* __restrict__ ald, int n) {
    constexpr int KC = 32;
    __shared__ float sX[64][KC + 1];
    __shared__ float sW[KC][132];
    int tid = threadIdx.x;
    int row0 = blockIdx.x * 64;
    int rg = tid >> 4;          // 0..15
    int cg = tid & 15;          // 0..15
    int r0 = rg * 4;
    int c0 = cg * 8;
    float acc[4][8];
#pragma unroll
    for (int i = 0; i < 4; ++i)
#pragma unroll
        for (int j = 0; j < 8; ++j) acc[i][j] = 0.f;

    for (int kc = 0; kc < K; kc += KC) {
        __syncthreads();
        // stage X tile: 64 rows x 32 k (512 float4, 2 per thread)
#pragma unroll
        for (int it = 0; it < 2; ++it) {
            int idx = tid + it * 256;
            int r = idx >> 3;
            int k4 = (idx & 7) * 4;
            int gr = row0 + r;
            float4 v = (gr < n) ? *reinterpret_cast<const float4*>(&X[(size_t)gr * K + kc + k4])
                                : make_float4(0.f, 0.f, 0.f, 0.f);
            sX[r][k4 + 0] = v.x; sX[r][k4 + 1] = v.y;
            sX[r][k4 + 2] = v.z; sX[r][k4 + 3] = v.w;
        }
        // stage W tile: 32 k x 128 cols (1024 float4, 4 per thread)
#pragma unroll
        for (int it = 0; it < 4; ++it) {
            int idx = tid + it * 256;
            int kk = idx >> 5;
            int c4 = (idx & 31) * 4;
            *reinterpret_cast<float4*>(&sW[kk][c4]) =
                *reinterpret_cast<const float4*>(&W[(size_t)(kc + kk) * 128 + c4]);
        }
        __syncthreads();
#pragma unroll
        for (int k = 0; k < KC; ++k) {
            float x0 = sX[r0 + 0][k];
            float x1 = sX[r0 + 1][k];
            float x2 = sX[r0 + 2][k];
            float x3 = sX[r0 + 3][k];
            float4 w0 = *reinterpret_cast<const float4*>(&sW[k][c0]);
            float4 w1 = *reinterpret_cast<const float4*>(&sW[k][c0 + 4]);
            acc[0][0] += x0 * w0.x; acc[0][1] += x0 * w0.y; acc[0][2] += x0 * w0.z; acc[0][3] += x0 * w0.w;
            acc[0][4] += x0 * w1.x; acc[0][5] += x0 * w1.y; acc[0][6] += x0 * w1.z; acc[0][7] += x0 * w1.w;
            acc[1][0] += x1 * w0.x; acc[1][1] += x1 * w0.y; acc[1][2] += x1 * w0.z; acc[1][3] += x1 * w0.w;
            acc[1][4] += x1 * w1.x; acc[1][5] += x1 * w1.y; acc[1][6] += x1 * w1.z; acc[1][7] += x1 * w1.w;
            acc[2][0] += x2 * w0.x; acc[2][1] += x2 * w0.y; acc[2][2] += x2 * w0.z; acc[2][3] += x2 * w0.w;
            acc[2][4] += x2 * w1.x; acc[2][5] += x2 * w1.y; acc[2][6] += x2 * w1.z; acc[2][7] += x2 * w1.w;
            acc[3][0] += x3 * w0.x; acc[3][1] += x3 * w0.y; acc[3][2] += x3 * w0.z; acc[3][3] += x3 * w0.w;
            acc[3][4] += x3 * w1.x; acc[3][5] += x3 * w1.y; acc[3][6] += x3 * w1.z; acc[3][7] += x3 * w1.w;
        }
    }

    // write H (2 float4 per row)
#pragma unroll
    for (int i = 0; i < 4; ++i) {
        int gr = row0 + r0 + i;
        if (gr < n) {
            float4* o = reinterpret_cast<float4*>(&H[(size_t)gr * 128 + c0]);
            o[0] = make_float4(acc[i][0], acc[i][1], acc[i][2], acc[i][3]);
            o[1] = make_float4(acc[i][4], acc[i][5], acc[i][6], acc[i][7]);
        }
    }

    // fused attention logits: head = c0/64; reduce partials over the 8
    // col-groups of each head (lanes cg&7) via shfl_xor. Lane layout within a
    // wave: lane = (rg&3)*16 + cg.
    float ps[4], pd[4];
#pragma unroll
    for (int i = 0; i < 4; ++i) {
        float s = 0.f, d = 0.f;
#pragma unroll
        for (int j = 0; j < 8; ++j) {
            float av = acc[i][j];
            s += av * a_src[c0 + j];
            d += av * a_dst[c0 + j];
        }
        ps[i] = s; pd[i] = d;
    }
#pragma unroll
    for (int off = 1; off <= 4; off <<= 1) {
#pragma unroll
        for (int i = 0; i < 4; ++i) {
            ps[i] += __shfl_xor(ps[i], off);
            pd[i] += __shfl_xor(pd[i], off);
        }
    }
    if ((cg & 7) == 0) {
        int head = cg >> 3;
#pragma unroll
        for (int i = 0; i < 4; ++i) {
            int gr = row0 + r0 + i;
            if (gr < n) {
                als[gr * 2 + head] = ps[i];
                ald[gr * 2 + head] = pd[i];
            }
        }
    }
}

// One wave per dst node. Lanes own edges for (e,max,p), then own channel
// pairs for the weighted feature gather; shfl broadcasts (src,p) per edge.
template <bool RELU>
__global__ __launch_bounds__(256) void agg_kernel(const float* __restrict__ Hf,
                                                  const float* __restrict__ als,
                                                  const float* __restrict__ ald,
                                                  const int* __restrict__ rowptr,
                                                  const int* __restrict__ csr_src,
                                                  const float* __restrict__ bias,
                                                  float* __restrict__ out, int n) {
    int wave = threadIdx.x >> 6, lane = threadIdx.x & 63;
    int node = blockIdx.x * 4 + wave;
    if (node >= n) return;
    int beg = rowptr[node], end = rowptr[node + 1];
    float ad0 = ald[node * 2], ad1 = ald[node * 2 + 1];

    float m0 = -INFINITY, m1 = -INFINITY;
    for (int c = beg; c < end; c += 64) {
        int j = c + lane;
        if (j < end) {
            int s = csr_src[j];
            float e0 = lrelu(als[s * 2] + ad0);
            float e1 = lrelu(als[s * 2 + 1] + ad1);
            m0 = fmaxf(m0, e0);
            m1 = fmaxf(m1, e1);
        }
    }
    for (int off = 32; off; off >>= 1) {
        m0 = fmaxf(m0, __shfl_xor(m0, off));
        m1 = fmaxf(m1, __shfl_xor(m1, off));
    }

    float z0 = 0.f, z1 = 0.f;
    float accx = 0.f, accy = 0.f;
    for (int c = beg; c < end; c += 64) {
        int j = c + lane;
        int s = 0;
        float p0 = 0.f, p1 = 0.f;
        if (j < end) {
            s = csr_src[j];
            float e0 = lrelu(als[s * 2] + ad0);
            float e1 = lrelu(als[s * 2 + 1] + ad1);
            p0 = __expf(e0 - m0);
            p1 = __expf(e1 - m1);
        }
        z0 += p0;
        z1 += p1;
        int cnt = min(64, end - c);
        for (int t = 0; t < cnt; ++t) {
            int sj = __shfl(s, t);
            float pj0 = __shfl(p0, t);
            float pj1 = __shfl(p1, t);
            float psel = (lane < 32) ? pj0 : pj1;
            const float2 hv = *reinterpret_cast<const float2*>(&Hf[(size_t)sj * 128 + lane * 2]);
            accx += psel * hv.x;
            accy += psel * hv.y;
        }
    }
    for (int off = 32; off; off >>= 1) {
        z0 += __shfl_xor(z0, off);
        z1 += __shfl_xor(z1, off);
    }
    float zsel = (lane < 32) ? z0 : z1;
    float vx = accx / zsel, vy = accy / zsel;
    float ox = vx + __shfl_xor(vx, 32);
    float oy = vy + __shfl_xor(vy, 32);
    if (lane < 32) {
        int ch = lane * 2;
        float r0 = 0.5f * ox + bias[ch];
        float r1 = 0.5f * oy + bias[ch + 1];
        if (RELU) {
            r0 = fmaxf(r0, 0.f);
            r1 = fmaxf(r1, 0.f);
        }
        *reinterpret_cast<float2*>(&out[(size_t)node * 64 + ch]) = make_float2(r0, r1);
    }
}

// preds = Hf [n,64] @ Wc [64,10] + bc; one thread per node.
__global__ __launch_bounds__(256) void cls_kernel(const float* __restrict__ Hf,
                                                  const float* __restrict__ Wc,
                                                  const float* __restrict__ bc,
                                                  float* __restrict__ out, int n) {
    __shared__ float sW[640];
    __shared__ float sb[10];
    int tid = threadIdx.x;
    for (int i = tid; i < 640; i += 256) sW[i] = Wc[i];
    if (tid < 10) sb[tid] = bc[tid];
    __syncthreads();
    int node = blockIdx.x * 256 + tid;
    if (node >= n) return;
    float acc[10];
#pragma unroll
    for (int j = 0; j < 10; ++j) acc[j] = sb[j];
    for (int k = 0; k < 64; k += 4) {
        float4 h4 = *reinterpret_cast<const float4*>(&Hf[(size_t)node * 64 + k]);
#pragma unroll
        for (int j = 0; j < 10; ++j) {
            acc[j] += h4.x * sW[(k + 0) * 10 + j];
            acc[j] += h4.y * sW[(k + 1) * 10 + j];
            acc[j] += h4.z * sW[(k + 2) * 10 + j];
            acc[j] += h4.w * sW[(k + 3) * 10 + j];
        }
    }
#pragma unroll
    for (int j = 0; j < 10; ++j) out[(size_t)node * 10 + j] = acc[j];
}

__global__ void ycopy_kernel(const int* __restrict__ y, float* __restrict__ out, int n) {
    int i = blockIdx.x * 256 + threadIdx.x;
    if (i < n) out[i] = (float)y[i];
}

extern "C" void kernel_launch(void* const* d_in, const int* in_sizes, int n_in,
                              void* d_out, int out_size, void* d_ws, size_t ws_size,
                              hipStream_t stream) {
    const float* x   = (const float*)d_in[0];
    const int*   ei  = (const int*)d_in[1];
    const int*   y   = (const int*)d_in[3];
    const float* W1  = (const float*)d_in[4];
    const float* as1 = (const float*)d_in[5];
    const float* ad1 = (const float*)d_in[6];
    const float* b1  = (const float*)d_in[7];
    const float* W2  = (const float*)d_in[8];
    const float* as2 = (const float*)d_in[9];
    const float* ad2 = (const float*)d_in[10];
    const float* b2  = (const float*)d_in[11];
    const float* Wc  = (const float*)d_in[12];
    const float* bc  = (const float*)d_in[13];

    int n = in_sizes[0] / 128;   // 50000
    int e = in_sizes[1] / 2;     // 850000
    const int* src = ei;
    const int* dst = ei + e;

    char* ws = (char*)d_ws;
    size_t off = 0;
    auto alloc = [&](size_t bytes) -> void* {
        void* p = ws + off;
        off = (off + bytes + 255) & ~size_t(255);
        return p;
    };
    float* A       = (float*)alloc((size_t)n * 128 * 4);  // h (pre-agg) both layers
    float* B       = (float*)alloc((size_t)n * 64 * 4);   // layer outputs
    float* als     = (float*)alloc((size_t)n * 2 * 4);
    float* ald     = (float*)alloc((size_t)n * 2 * 4);
    int*   rowptr  = (int*)alloc((size_t)(n + 1) * 4);
    int*   cursor  = (int*)alloc((size_t)n * 4);
    int*   deg     = (int*)alloc((size_t)n * 4);
    int*   bsum    = (int*)alloc((size_t)256 * 4);
    int*   csr_src = (int*)alloc((size_t)e * 4);

    float* preds = (float*)d_out;
    float* yout  = preds + (size_t)n * 10;

    int eb = (e + 255) / 256;
    int nb4 = (n + 3) / 4;
    int nb64 = (n + 63) / 64;
    int nb256 = (n + 255) / 256;  // also the scan block count

    // CSR by dst (rebuilt every call: no cross-call state allowed)
    hipMemsetAsync(deg, 0, (size_t)n * 4, stream);
    deg_kernel<<<eb, 256, 0, stream>>>(dst, deg, e);
    block_sums<<<nb256, 256, 0, stream>>>(deg, bsum, n);
    scan_partials<<<1, 256, 0, stream>>>(bsum, rowptr, nb256, n);
    scan_blocks<<<nb256, 256, 0, stream>>>(deg, bsum, rowptr, cursor, n);
    scatter_kernel<<<eb, 256, 0, stream>>>(src, dst, cursor, csr_src, e);

    // layer 1
    gemm_nodes<128><<<nb64, 256, 0, stream>>>(x, W1, as1, ad1, A, als, ald, n);
    agg_kernel<true><<<nb4, 256, 0, stream>>>(A, als, ald, rowptr, csr_src, b1, B, n);

    // layer 2
    gemm_nodes<64><<<nb64, 256, 0, stream>>>(B, W2, as2, ad2, A, als, ald, n);
    agg_kernel<false><<<nb4, 256, 0, stream>>>(A, als, ald, rowptr, csr_src, b2, B, n);

    // classifier + y passthrough
    cls_kernel<<<nb256, 256, 0, stream>>>(B, Wc, bc, preds, n);
    ycopy_kernel<<<nb256, 256, 0, stream>>>(y, yout, n);
}

// Round 4
// 255.283 us; speedup vs baseline: 1.9517x; 1.1779x over previous
//
#include <hip/hip_runtime.h>
#include <math.h>

// ---------------------------------------------------------------------------
// GAT node classifier: 2x GATConv(H=2, concat=False/head-mean) + Linear.
//   1. CSR by dst: degree atomics -> hierarchical parallel scan -> scatter
//   2. h = X @ W (fp32, 64 rows/block, 4x8 reg tile) + fused attention logits
//   3. agg: ONE BLOCK PER GRAPH (100 nodes); stage h/als/ald of the graph in
//      LDS, then segment softmax + weighted gather entirely from LDS.
//   4. preds = B @ Wc + bc ; y passthrough
// ---------------------------------------------------------------------------

#define NPG 100   // nodes per graph (fixed by problem)

__device__ __forceinline__ float lrelu(float x) { return x > 0.f ? x : 0.2f * x; }

__global__ void deg_kernel(const int* __restrict__ dst, int* cnt, int e) {
    int i = blockIdx.x * 256 + threadIdx.x;
    if (i < e) atomicAdd(&cnt[dst[i]], 1);
}

__global__ __launch_bounds__(256) void block_sums(const int* __restrict__ deg,
                                                  int* __restrict__ bsum, int n) {
    int i = blockIdx.x * 256 + threadIdx.x;
    int v = (i < n) ? deg[i] : 0;
    for (int off = 32; off; off >>= 1) v += __shfl_xor(v, off);
    __shared__ int ws[4];
    if ((threadIdx.x & 63) == 0) ws[threadIdx.x >> 6] = v;
    __syncthreads();
    if (threadIdx.x == 0) bsum[blockIdx.x] = ws[0] + ws[1] + ws[2] + ws[3];
}

__global__ __launch_bounds__(256) void scan_partials(int* bsum, int* rowptr, int nb, int n) {
    __shared__ int s[256];
    int tid = threadIdx.x;
    s[tid] = (tid < nb) ? bsum[tid] : 0;
    __syncthreads();
    if (tid == 0) {
        int acc = 0;
        for (int j = 0; j < nb; ++j) { int t = s[j]; s[j] = acc; acc += t; }
        rowptr[n] = acc;
    }
    __syncthreads();
    if (tid < nb) bsum[tid] = s[tid];
}

__global__ __launch_bounds__(256) void scan_blocks(const int* __restrict__ deg,
                                                   const int* __restrict__ bsum,
                                                   int* __restrict__ rowptr,
                                                   int* __restrict__ cursor, int n) {
    int tid = threadIdx.x;
    int i = blockIdx.x * 256 + tid;
    int v = (i < n) ? deg[i] : 0;
    int lane = tid & 63, w = tid >> 6;
    int x = v;
    for (int off = 1; off < 64; off <<= 1) {
        int t = __shfl_up(x, off);
        if (lane >= off) x += t;
    }
    __shared__ int wsum[4];
    if (lane == 63) wsum[w] = x;
    __syncthreads();
    int wo = 0;
    for (int j = 0; j < w; ++j) wo += wsum[j];
    int excl = bsum[blockIdx.x] + wo + x - v;
    if (i < n) { rowptr[i] = excl; cursor[i] = excl; }
}

__global__ void scatter_kernel(const int* __restrict__ src, const int* __restrict__ dst,
                               int* cursor, int* __restrict__ csr_src, int e) {
    int i = blockIdx.x * 256 + threadIdx.x;
    if (i < e) {
        int d = dst[i];
        int pos = atomicAdd(&cursor[d], 1);
        csr_src[pos] = src[i];
    }
}

// X [n,K] @ W [K,128] -> H [n,128], fused attention logits.
template <int K>
__global__ __launch_bounds__(256) void gemm_nodes(const float* __restrict__ X,
                                                  const float* __restrict__ W,
                                                  const float* __restrict__ a_src,
                                                  const float* __restrict__ a_dst,
                                                  float* __restrict__ H,
                                                  float* __restrict__ als,
                                                  float* __restrict__ ald, int n) {
    constexpr int KC = 32;
    __shared__ float sX[64][KC + 1];
    __shared__ float sW[KC][132];
    int tid = threadIdx.x;
    int row0 = blockIdx.x * 64;
    int rg = tid >> 4;
    int cg = tid & 15;
    int r0 = rg * 4;
    int c0 = cg * 8;
    float acc[4][8];
#pragma unroll
    for (int i = 0; i < 4; ++i)
#pragma unroll
        for (int j = 0; j < 8; ++j) acc[i][j] = 0.f;

    for (int kc = 0; kc < K; kc += KC) {
        __syncthreads();
#pragma unroll
        for (int it = 0; it < 2; ++it) {
            int idx = tid + it * 256;
            int r = idx >> 3;
            int k4 = (idx & 7) * 4;
            int gr = row0 + r;
            float4 v = (gr < n) ? *reinterpret_cast<const float4*>(&X[(size_t)gr * K + kc + k4])
                                : make_float4(0.f, 0.f, 0.f, 0.f);
            sX[r][k4 + 0] = v.x; sX[r][k4 + 1] = v.y;
            sX[r][k4 + 2] = v.z; sX[r][k4 + 3] = v.w;
        }
#pragma unroll
        for (int it = 0; it < 4; ++it) {
            int idx = tid + it * 256;
            int kk = idx >> 5;
            int c4 = (idx & 31) * 4;
            *reinterpret_cast<float4*>(&sW[kk][c4]) =
                *reinterpret_cast<const float4*>(&W[(size_t)(kc + kk) * 128 + c4]);
        }
        __syncthreads();
#pragma unroll
        for (int k = 0; k < KC; ++k) {
            float x0 = sX[r0 + 0][k];
            float x1 = sX[r0 + 1][k];
            float x2 = sX[r0 + 2][k];
            float x3 = sX[r0 + 3][k];
            float4 w0 = *reinterpret_cast<const float4*>(&sW[k][c0]);
            float4 w1 = *reinterpret_cast<const float4*>(&sW[k][c0 + 4]);
            acc[0][0] += x0 * w0.x; acc[0][1] += x0 * w0.y; acc[0][2] += x0 * w0.z; acc[0][3] += x0 * w0.w;
            acc[0][4] += x0 * w1.x; acc[0][5] += x0 * w1.y; acc[0][6] += x0 * w1.z; acc[0][7] += x0 * w1.w;
            acc[1][0] += x1 * w0.x; acc[1][1] += x1 * w0.y; acc[1][2] += x1 * w0.z; acc[1][3] += x1 * w0.w;
            acc[1][4] += x1 * w1.x; acc[1][5] += x1 * w1.y; acc[1][6] += x1 * w1.z; acc[1][7] += x1 * w1.w;
            acc[2][0] += x2 * w0.x; acc[2][1] += x2 * w0.y; acc[2][2] += x2 * w0.z; acc[2][3] += x2 * w0.w;
            acc[2][4] += x2 * w1.x; acc[2][5] += x2 * w1.y; acc[2][6] += x2 * w1.z; acc[2][7] += x2 * w1.w;
            acc[3][0] += x3 * w0.x; acc[3][1] += x3 * w0.y; acc[3][2] += x3 * w0.z; acc[3][3] += x3 * w0.w;
            acc[3][4] += x3 * w1.x; acc[3][5] += x3 * w1.y; acc[3][6] += x3 * w1.z; acc[3][7] += x3 * w1.w;
        }
    }

#pragma unroll
    for (int i = 0; i < 4; ++i) {
        int gr = row0 + r0 + i;
        if (gr < n) {
            float4* o = reinterpret_cast<float4*>(&H[(size_t)gr * 128 + c0]);
            o[0] = make_float4(acc[i][0], acc[i][1], acc[i][2], acc[i][3]);
            o[1] = make_float4(acc[i][4], acc[i][5], acc[i][6], acc[i][7]);
        }
    }

    float ps[4], pd[4];
#pragma unroll
    for (int i = 0; i < 4; ++i) {
        float s = 0.f, d = 0.f;
#pragma unroll
        for (int j = 0; j < 8; ++j) {
            float av = acc[i][j];
            s += av * a_src[c0 + j];
            d += av * a_dst[c0 + j];
        }
        ps[i] = s; pd[i] = d;
    }
#pragma unroll
    for (int off = 1; off <= 4; off <<= 1) {
#pragma unroll
        for (int i = 0; i < 4; ++i) {
            ps[i] += __shfl_xor(ps[i], off);
            pd[i] += __shfl_xor(pd[i], off);
        }
    }
    if ((cg & 7) == 0) {
        int head = cg >> 3;
#pragma unroll
        for (int i = 0; i < 4; ++i) {
            int gr = row0 + r0 + i;
            if (gr < n) {
                als[gr * 2 + head] = ps[i];
                ald[gr * 2 + head] = pd[i];
            }
        }
    }
}

// One block per graph. Stage the graph's h [NPG,128] + als/ald in LDS, then
// 8 waves each process dst nodes (stride 8). Gather loop: 2 edges/iter,
// lane-half owns one edge, 32 lanes x float4 cover its 128 channels.
template <bool RELU>
__global__ __launch_bounds__(512) void agg_graph(const float* __restrict__ Hf,
                                                 const float* __restrict__ als,
                                                 const float* __restrict__ ald,
                                                 const int* __restrict__ rowptr,
                                                 const int* __restrict__ csr_src,
                                                 const float* __restrict__ bias,
                                                 float* __restrict__ out, int n) {
    __shared__ float sH[NPG][128];
    __shared__ float sAs[NPG * 2];
    __shared__ float sAd[NPG * 2];
    int g = blockIdx.x;
    int gbase = g * NPG;
    int tid = threadIdx.x;
    int wave = tid >> 6, lane = tid & 63;

    // stage h (NPG*32 float4) + logits
    for (int i = tid; i < NPG * 32; i += 512) {
        int r = i >> 5, c4 = (i & 31) * 4;
        *reinterpret_cast<float4*>(&sH[r][c4]) =
            *reinterpret_cast<const float4*>(&Hf[(size_t)(gbase + r) * 128 + c4]);
    }
    for (int i = tid; i < NPG * 2; i += 512) {
        sAs[i] = als[gbase * 2 + i];
        sAd[i] = ald[gbase * 2 + i];
    }
    __syncthreads();

    int q = lane & 31;          // channel group: ch 4q..4q+3
    int half = lane >> 5;       // edge parity within pair-iteration
    float4 bv = *reinterpret_cast<const float4*>(&bias[((q < 16) ? q : q - 16) * 4]);

    for (int d = wave; d < NPG; d += 8) {
        int node = gbase + d;
        int beg = rowptr[node], end = rowptr[node + 1];
        float ad0 = sAd[d * 2], ad1 = sAd[d * 2 + 1];

        // chunk 0 logits in registers
        int j0 = beg + lane;
        int s0 = 0;
        float ea0 = -INFINITY, ea1 = -INFINITY;
        if (j0 < end) {
            s0 = csr_src[j0] - gbase;
            ea0 = lrelu(sAs[s0 * 2] + ad0);
            ea1 = lrelu(sAs[s0 * 2 + 1] + ad1);
        }
        float m0 = ea0, m1 = ea1;
        for (int c = beg + 64; c < end; c += 64) {   // rare (deg > 64)
            int j = c + lane;
            if (j < end) {
                int s = csr_src[j] - gbase;
                m0 = fmaxf(m0, lrelu(sAs[s * 2] + ad0));
                m1 = fmaxf(m1, lrelu(sAs[s * 2 + 1] + ad1));
            }
        }
        for (int off = 32; off; off >>= 1) {
            m0 = fmaxf(m0, __shfl_xor(m0, off));
            m1 = fmaxf(m1, __shfl_xor(m1, off));
        }

        float p0 = __expf(ea0 - m0);   // exp(-inf - m) = 0 for inactive lanes
        float p1 = __expf(ea1 - m1);
        float z0 = p0, z1 = p1;

        float acc[4] = {0.f, 0.f, 0.f, 0.f};
        // gather chunk 0: 2 edges per iteration
        int cnt = min(64, end - beg);
        for (int t = 0; t < cnt; t += 2) {
            int tl = t + half;
            int sj = __shfl(s0, tl);
            float pj0 = __shfl(p0, tl);
            float pj1 = __shfl(p1, tl);
            float psel = (q < 16) ? pj0 : pj1;
            float4 hv = *reinterpret_cast<const float4*>(&sH[sj][q * 4]);
            acc[0] += psel * hv.x; acc[1] += psel * hv.y;
            acc[2] += psel * hv.z; acc[3] += psel * hv.w;
        }
        // further chunks (rare)
        for (int c = beg + 64; c < end; c += 64) {
            int j = c + lane;
            int s = 0;
            float q0 = 0.f, q1 = 0.f;
            if (j < end) {
                s = csr_src[j] - gbase;
                q0 = __expf(lrelu(sAs[s * 2] + ad0) - m0);
                q1 = __expf(lrelu(sAs[s * 2 + 1] + ad1) - m1);
            }
            z0 += q0; z1 += q1;
            int cc = min(64, end - c);
            for (int t = 0; t < cc; t += 2) {
                int tl = t + half;
                int sj = __shfl(s, tl);
                float pj0 = __shfl(q0, tl);
                float pj1 = __shfl(q1, tl);
                float psel = (q < 16) ? pj0 : pj1;
                float4 hv = *reinterpret_cast<const float4*>(&sH[sj][q * 4]);
                acc[0] += psel * hv.x; acc[1] += psel * hv.y;
                acc[2] += psel * hv.z; acc[3] += psel * hv.w;
            }
        }

        for (int off = 32; off; off >>= 1) {
            z0 += __shfl_xor(z0, off);
            z1 += __shfl_xor(z1, off);
        }
        // combine edge parities (lane ^ 32), normalize per head, head-mean (lane ^ 16)
        float zsel = (q < 16) ? z0 : z1;
#pragma unroll
        for (int c = 0; c < 4; ++c) {
            acc[c] += __shfl_xor(acc[c], 32);
            acc[c] /= zsel;
            acc[c] += __shfl_xor(acc[c], 16);
        }
        if (lane < 16) {
            float4 r;
            r.x = 0.5f * acc[0] + bv.x;
            r.y = 0.5f * acc[1] + bv.y;
            r.z = 0.5f * acc[2] + bv.z;
            r.w = 0.5f * acc[3] + bv.w;
            if (RELU) {
                r.x = fmaxf(r.x, 0.f); r.y = fmaxf(r.y, 0.f);
                r.z = fmaxf(r.z, 0.f); r.w = fmaxf(r.w, 0.f);
            }
            *reinterpret_cast<float4*>(&out[(size_t)node * 64 + lane * 4]) = r;
        }
    }
}

// preds = Hf [n,64] @ Wc [64,10] + bc; one thread per node.
__global__ __launch_bounds__(256) void cls_kernel(const float* __restrict__ Hf,
                                                  const float* __restrict__ Wc,
                                                  const float* __restrict__ bc,
                                                  float* __restrict__ out, int n) {
    __shared__ float sW[640];
    __shared__ float sb[10];
    int tid = threadIdx.x;
    for (int i = tid; i < 640; i += 256) sW[i] = Wc[i];
    if (tid < 10) sb[tid] = bc[tid];
    __syncthreads();
    int node = blockIdx.x * 256 + tid;
    if (node >= n) return;
    float acc[10];
#pragma unroll
    for (int j = 0; j < 10; ++j) acc[j] = sb[j];
    for (int k = 0; k < 64; k += 4) {
        float4 h4 = *reinterpret_cast<const float4*>(&Hf[(size_t)node * 64 + k]);
#pragma unroll
        for (int j = 0; j < 10; ++j) {
            acc[j] += h4.x * sW[(k + 0) * 10 + j];
            acc[j] += h4.y * sW[(k + 1) * 10 + j];
            acc[j] += h4.z * sW[(k + 2) * 10 + j];
            acc[j] += h4.w * sW[(k + 3) * 10 + j];
        }
    }
#pragma unroll
    for (int j = 0; j < 10; ++j) out[(size_t)node * 10 + j] = acc[j];
}

__global__ void ycopy_kernel(const int* __restrict__ y, float* __restrict__ out, int n) {
    int i = blockIdx.x * 256 + threadIdx.x;
    if (i < n) out[i] = (float)y[i];
}

extern "C" void kernel_launch(void* const* d_in, const int* in_sizes, int n_in,
                              void* d_out, int out_size, void* d_ws, size_t ws_size,
                              hipStream_t stream) {
    const float* x   = (const float*)d_in[0];
    const int*   ei  = (const int*)d_in[1];
    const int*   y   = (const int*)d_in[3];
    const float* W1  = (const float*)d_in[4];
    const float* as1 = (const float*)d_in[5];
    const float* ad1 = (const float*)d_in[6];
    const float* b1  = (const float*)d_in[7];
    const float* W2  = (const float*)d_in[8];
    const float* as2 = (const float*)d_in[9];
    const float* ad2 = (const float*)d_in[10];
    const float* b2  = (const float*)d_in[11];
    const float* Wc  = (const float*)d_in[12];
    const float* bc  = (const float*)d_in[13];

    int n = in_sizes[0] / 128;   // 50000
    int e = in_sizes[1] / 2;     // 850000
    int G = n / NPG;             // 500 graphs
    const int* src = ei;
    const int* dst = ei + e;

    char* ws = (char*)d_ws;
    size_t off = 0;
    auto alloc = [&](size_t bytes) -> void* {
        void* p = ws + off;
        off = (off + bytes + 255) & ~size_t(255);
        return p;
    };
    float* A       = (float*)alloc((size_t)n * 128 * 4);
    float* B       = (float*)alloc((size_t)n * 64 * 4);
    float* als     = (float*)alloc((size_t)n * 2 * 4);
    float* ald     = (float*)alloc((size_t)n * 2 * 4);
    int*   rowptr  = (int*)alloc((size_t)(n + 1) * 4);
    int*   cursor  = (int*)alloc((size_t)n * 4);
    int*   deg     = (int*)alloc((size_t)n * 4);
    int*   bsum    = (int*)alloc((size_t)256 * 4);
    int*   csr_src = (int*)alloc((size_t)e * 4);

    float* preds = (float*)d_out;
    float* yout  = preds + (size_t)n * 10;

    int eb = (e + 255) / 256;
    int nb64 = (n + 63) / 64;
    int nb256 = (n + 255) / 256;

    // CSR by dst (rebuilt every call: no cross-call state allowed)
    hipMemsetAsync(deg, 0, (size_t)n * 4, stream);
    deg_kernel<<<eb, 256, 0, stream>>>(dst, deg, e);
    block_sums<<<nb256, 256, 0, stream>>>(deg, bsum, n);
    scan_partials<<<1, 256, 0, stream>>>(bsum, rowptr, nb256, n);
    scan_blocks<<<nb256, 256, 0, stream>>>(deg, bsum, rowptr, cursor, n);
    scatter_kernel<<<eb, 256, 0, stream>>>(src, dst, cursor, csr_src, e);

    // layer 1
    gemm_nodes<128><<<nb64, 256, 0, stream>>>(x, W1, as1, ad1, A, als, ald, n);
    agg_graph<true><<<G, 512, 0, stream>>>(A, als, ald, rowptr, csr_src, b1, B, n);

    // layer 2
    gemm_nodes<64><<<nb64, 256, 0, stream>>>(B, W2, as2, ad2, A, als, ald, n);
    agg_graph<false><<<G, 512, 0, stream>>>(A, als, ald, rowptr, csr_src, b2, B, n);

    // classifier + y passthrough
    cls_kernel<<<nb256, 256, 0, stream>>>(B, Wc, bc, preds, n);
    ycopy_kernel<<<nb256, 256, 0, stream>>>(y, yout, n);
}